// Round 1
// baseline (217.853 us; speedup 1.0000x reference)
//
#include <hip/hip_runtime.h>

// MechanicsFunctionsMultiBlock: per-element Neo-Hookean energy Hessian (2D, NEN=3, NQP=1).
// Closed-form Hessian:
//   H[n,c,m,d] = vol * ( mu_eff * (c==d) * dot(G[n],G[m])
//                      + (mu_eff - lam*logJ) * P[n,d]*P[m,c]
//                      + lam * P[n,c]*P[m,d] )
// with F = I + gradU, P = G * F^{-1}, mu_eff = mu*(1 + 0.01*state).

constexpr int E_CNT  = 800000;
constexpr int HALF_E = 400000;

__global__ __launch_bounds__(256) void mark_blocks_kernel(
    const int* __restrict__ b0, const int* __restrict__ b1,
    unsigned char* __restrict__ flag) {
  int i = blockIdx.x * blockDim.x + threadIdx.x;
  if (i < HALF_E) {
    flag[b0[i]] = 0;   // block0: lam=1.0, mu=0.5
    flag[b1[i]] = 1;   // block1: lam=2.0, mu=1.0
  }
}

__global__ __launch_bounds__(256) void hess_kernel(
    const float* __restrict__ U, const float* __restrict__ state,
    const int* __restrict__ conns, const float* __restrict__ grads,
    const float* __restrict__ vols, const unsigned char* __restrict__ flag,
    float* __restrict__ out) {
  int e = blockIdx.x * blockDim.x + threadIdx.x;
  if (e >= E_CNT) return;

  const bool b  = flag[e] != 0;
  const float lam = b ? 2.0f : 1.0f;
  const float mu  = b ? 1.0f : 0.5f;

  const int n0 = conns[3 * e + 0];
  const int n1 = conns[3 * e + 1];
  const int n2 = conns[3 * e + 2];
  // U is (N,2) row-major; rows are 8B-aligned.
  const float2 d0 = *(const float2*)(U + 2 * n0);
  const float2 d1 = *(const float2*)(U + 2 * n1);
  const float2 d2 = *(const float2*)(U + 2 * n2);
  // shapeGrads (E,1,3,2): 6 floats per element, 8B-aligned offsets.
  const float2* gp = (const float2*)(grads + 6 * e);
  const float2 g0 = gp[0], g1 = gp[1], g2 = gp[2];

  // gradU[c][d] = sum_n D[n][c] * G[n][d]
  const float gu00 = d0.x * g0.x + d1.x * g1.x + d2.x * g2.x;
  const float gu01 = d0.x * g0.y + d1.x * g1.y + d2.x * g2.y;
  const float gu10 = d0.y * g0.x + d1.y * g1.x + d2.y * g2.x;
  const float gu11 = d0.y * g0.y + d1.y * g1.y + d2.y * g2.y;

  const float F00 = 1.0f + gu00, F01 = gu01, F10 = gu10, F11 = 1.0f + gu11;
  const float J    = F00 * F11 - F01 * F10;
  const float logJ = logf(J);
  const float rJ   = 1.0f / J;
  const float Fi00 =  F11 * rJ, Fi01 = -F01 * rJ;
  const float Fi10 = -F10 * rJ, Fi11 =  F00 * rJ;

  // P[n][c] = G[n][0]*Finv[0][c] + G[n][1]*Finv[1][c]
  float P[3][2];
  P[0][0] = g0.x * Fi00 + g0.y * Fi10;  P[0][1] = g0.x * Fi01 + g0.y * Fi11;
  P[1][0] = g1.x * Fi00 + g1.y * Fi10;  P[1][1] = g1.x * Fi01 + g1.y * Fi11;
  P[2][0] = g2.x * Fi00 + g2.y * Fi10;  P[2][1] = g2.x * Fi01 + g2.y * Fi11;

  const float gx[3] = {g0.x, g1.x, g2.x};
  const float gy[3] = {g0.y, g1.y, g2.y};

  const float mu_eff = mu * (1.0f + 0.01f * state[e]);
  const float c2     = mu_eff - lam * logJ;
  const float vol    = vols[e];

  float h[36];
#pragma unroll
  for (int n = 0; n < 3; ++n) {
#pragma unroll
    for (int m = 0; m < 3; ++m) {
      const float dg = gx[n] * gx[m] + gy[n] * gy[m];
#pragma unroll
      for (int c = 0; c < 2; ++c) {
#pragma unroll
        for (int d = 0; d < 2; ++d) {
          float v = c2 * P[n][d] * P[m][c] + lam * P[n][c] * P[m][d];
          if (c == d) v += mu_eff * dg;
          h[n * 12 + c * 6 + m * 2 + d] = vol * v;
        }
      }
    }
  }

  // 36 contiguous floats per element; 144B is 16B-aligned -> 9 x float4 stores.
  float4* op = (float4*)(out + 36 * e);
#pragma unroll
  for (int i = 0; i < 9; ++i)
    op[i] = make_float4(h[4 * i + 0], h[4 * i + 1], h[4 * i + 2], h[4 * i + 3]);
}

extern "C" void kernel_launch(void* const* d_in, const int* in_sizes, int n_in,
                              void* d_out, int out_size, void* d_ws, size_t ws_size,
                              hipStream_t stream) {
  const float* U     = (const float*)d_in[0];
  // d_in[1] = coords   (unused by the Hessian)
  const float* state = (const float*)d_in[2];
  const int*   conns = (const int*)d_in[3];
  // d_in[4] = shapes   (unused by the Hessian)
  const float* grads = (const float*)d_in[5];
  const float* vols  = (const float*)d_in[6];
  const int*   b0    = (const int*)d_in[7];
  const int*   b1    = (const int*)d_in[8];
  float* out = (float*)d_out;
  unsigned char* flag = (unsigned char*)d_ws;  // E bytes of scratch

  mark_blocks_kernel<<<(HALF_E + 255) / 256, 256, 0, stream>>>(b0, b1, flag);
  hess_kernel<<<(E_CNT + 255) / 256, 256, 0, stream>>>(U, state, conns, grads,
                                                       vols, flag, out);
}

// Round 2
// 190.548 us; speedup vs baseline: 1.1433x; 1.1433x over previous
//
#include <hip/hip_runtime.h>

// MechanicsFunctionsMultiBlock: per-element Neo-Hookean energy Hessian (2D, NEN=3, NQP=1).
// Closed-form Hessian:
//   H[n,c,m,d] = vol * ( mu_eff * (c==d) * dot(G[n],G[m])
//                      + (mu_eff - lam*logJ) * P[n,d]*P[m,c]
//                      + lam * P[n,c]*P[m,d] )
// with F = I + gradU, P = G * F^{-1}, mu_eff = mu*(1 + 0.01*state).
//
// R2: output staged through LDS (stride-37 pad) -> fully coalesced float4
// stores; flag pass split into coalesced zero + single-block scatter.

constexpr int E_CNT  = 800000;
constexpr int HALF_E = 400000;

__global__ __launch_bounds__(256) void zero_flags_kernel(uint4* __restrict__ flag4) {
  int i = blockIdx.x * blockDim.x + threadIdx.x;
  if (i < E_CNT / 16) flag4[i] = make_uint4(0, 0, 0, 0);
}

__global__ __launch_bounds__(256) void mark_b1_kernel(
    const int* __restrict__ b1, unsigned char* __restrict__ flag) {
  int i = blockIdx.x * blockDim.x + threadIdx.x;
  if (i < HALF_E) flag[b1[i]] = 1;  // block1: lam=2.0, mu=1.0
}

__global__ __launch_bounds__(256) void hess_kernel(
    const float* __restrict__ U, const float* __restrict__ state,
    const int* __restrict__ conns, const float* __restrict__ grads,
    const float* __restrict__ vols, const unsigned char* __restrict__ flag,
    float* __restrict__ out) {
  __shared__ float lds[256 * 37];  // 37888 B -> 4 blocks/CU
  const int tid = threadIdx.x;
  const int e = blockIdx.x * 256 + tid;  // E = 3125*256 exactly, no tail

  const bool b  = flag[e] != 0;
  const float lam = b ? 2.0f : 1.0f;
  const float mu  = b ? 1.0f : 0.5f;

  const int n0 = conns[3 * e + 0];
  const int n1 = conns[3 * e + 1];
  const int n2 = conns[3 * e + 2];
  const float2 d0 = *(const float2*)(U + 2 * n0);
  const float2 d1 = *(const float2*)(U + 2 * n1);
  const float2 d2 = *(const float2*)(U + 2 * n2);
  const float2* gp = (const float2*)(grads + 6 * e);
  const float2 g0 = gp[0], g1 = gp[1], g2 = gp[2];

  // gradU[c][d] = sum_n D[n][c] * G[n][d]
  const float gu00 = d0.x * g0.x + d1.x * g1.x + d2.x * g2.x;
  const float gu01 = d0.x * g0.y + d1.x * g1.y + d2.x * g2.y;
  const float gu10 = d0.y * g0.x + d1.y * g1.x + d2.y * g2.x;
  const float gu11 = d0.y * g0.y + d1.y * g1.y + d2.y * g2.y;

  const float F00 = 1.0f + gu00, F01 = gu01, F10 = gu10, F11 = 1.0f + gu11;
  const float J    = F00 * F11 - F01 * F10;
  const float logJ = logf(J);
  const float rJ   = 1.0f / J;
  const float Fi00 =  F11 * rJ, Fi01 = -F01 * rJ;
  const float Fi10 = -F10 * rJ, Fi11 =  F00 * rJ;

  // P[n][c] = G[n][0]*Finv[0][c] + G[n][1]*Finv[1][c]
  float P[3][2];
  P[0][0] = g0.x * Fi00 + g0.y * Fi10;  P[0][1] = g0.x * Fi01 + g0.y * Fi11;
  P[1][0] = g1.x * Fi00 + g1.y * Fi10;  P[1][1] = g1.x * Fi01 + g1.y * Fi11;
  P[2][0] = g2.x * Fi00 + g2.y * Fi10;  P[2][1] = g2.x * Fi01 + g2.y * Fi11;

  const float gx[3] = {g0.x, g1.x, g2.x};
  const float gy[3] = {g0.y, g1.y, g2.y};

  const float mu_eff = mu * (1.0f + 0.01f * state[e]);
  const float c2     = mu_eff - lam * logJ;
  const float vol    = vols[e];

  // h[n*12 + c*6 + m*2 + d], written to LDS at stride 37 (bank = (5t+k)%32,
  // worst-case 2-way across 64 lanes -> conflict-free in practice).
  float* hl = lds + tid * 37;
#pragma unroll
  for (int n = 0; n < 3; ++n) {
#pragma unroll
    for (int m = 0; m < 3; ++m) {
      const float dg = gx[n] * gx[m] + gy[n] * gy[m];
#pragma unroll
      for (int c = 0; c < 2; ++c) {
#pragma unroll
        for (int d = 0; d < 2; ++d) {
          float v = c2 * P[n][d] * P[m][c] + lam * P[n][c] * P[m][d];
          if (c == d) v += mu_eff * dg;
          hl[n * 12 + c * 6 + m * 2 + d] = vol * v;
        }
      }
    }
  }

  __syncthreads();

  // Block writes 256*36 = 9216 contiguous floats = 2304 float4, 9 per thread,
  // fully coalesced. LDS address for flat float f is f + f/36.
  float4* ob = (float4*)(out + 36 * (size_t)(blockIdx.x * 256));
#pragma unroll
  for (int i = 0; i < 9; ++i) {
    const int f = 4 * (tid + i * 256);
    float4 v;
    v.x = lds[(f + 0) + (f + 0) / 36];
    v.y = lds[(f + 1) + (f + 1) / 36];
    v.z = lds[(f + 2) + (f + 2) / 36];
    v.w = lds[(f + 3) + (f + 3) / 36];
    ob[tid + i * 256] = v;
  }
}

extern "C" void kernel_launch(void* const* d_in, const int* in_sizes, int n_in,
                              void* d_out, int out_size, void* d_ws, size_t ws_size,
                              hipStream_t stream) {
  const float* U     = (const float*)d_in[0];
  // d_in[1] = coords   (unused by the Hessian)
  const float* state = (const float*)d_in[2];
  const int*   conns = (const int*)d_in[3];
  // d_in[4] = shapes   (unused by the Hessian)
  const float* grads = (const float*)d_in[5];
  const float* vols  = (const float*)d_in[6];
  // d_in[7] = blocks0  (flag defaults to 0)
  const int*   b1    = (const int*)d_in[8];
  float* out = (float*)d_out;
  unsigned char* flag = (unsigned char*)d_ws;  // E bytes of scratch

  zero_flags_kernel<<<(E_CNT / 16 + 255) / 256, 256, 0, stream>>>((uint4*)flag);
  mark_b1_kernel<<<(HALF_E + 255) / 256, 256, 0, stream>>>(b1, flag);
  hess_kernel<<<E_CNT / 256, 256, 0, stream>>>(U, state, conns, grads,
                                               vols, flag, out);
}